// Round 1
// baseline (322.655 us; speedup 1.0000x reference)
//
#include <hip/hip_runtime.h>
#include <hip/hip_bf16.h>

// ---------------------------------------------------------------------------
// SelfAttentionHybrid: single-head attention, B=4 S=2048 E=1024, fp32 in/out.
// Strategy: cast to bf16, run all matmuls as m97-style MFMA GEMMs
// (128x128 tile, BK=64, global_load_lds width=16, XOR-swizzled LDS),
// softmax as a memory-bound row kernel. fp32 accumulate everywhere.
// ---------------------------------------------------------------------------

typedef __bf16 bf16_t;
typedef __bf16 bf16x8 __attribute__((ext_vector_type(8)));
typedef __bf16 bf16x4 __attribute__((ext_vector_type(4)));
typedef float  f32x4  __attribute__((ext_vector_type(4)));

__device__ __forceinline__ void async_copy16(const void* g, void* l) {
  __builtin_amdgcn_global_load_lds(
      (const __attribute__((address_space(1))) void*)g,
      (__attribute__((address_space(3))) void*)l, 16, 0, 0);
}

__device__ __forceinline__ void store_out(float* p, float v)  { *p = v; }
__device__ __forceinline__ void store_out(bf16_t* p, float v) { *p = (bf16_t)v; }

// ---------------------------------------------------------------------------
// C[M,N] = (A[M,K] bf16 row-major) x (B[N,K] bf16 row-major)^T * scale + bias
// Batched via blockIdx.z with element strides. M%128==0, N%128==0, K%64==0.
// Block = 256 threads (4 waves, 2x2), each wave computes 64x64 (4x4 MFMA tiles).
// ---------------------------------------------------------------------------
#define BM 128
#define BN 128
#define BKT 64   // K-tile

template <typename OutT, bool HasBias>
__global__ __launch_bounds__(256) void gemm_bt(
    const bf16_t* __restrict__ A, const bf16_t* __restrict__ B,
    OutT* __restrict__ C, const float* __restrict__ bias,
    int M, int N, int K, float scale,
    long long strideA, long long strideB, long long strideC) {
  const int z = blockIdx.z;
  A += (long long)z * strideA;
  B += (long long)z * strideB;
  C += (long long)z * strideC;

  __shared__ __align__(16) bf16_t As[BM * BKT];  // 16 KB
  __shared__ __align__(16) bf16_t Bs[BN * BKT];  // 16 KB

  const int t    = threadIdx.x;
  const int lane = t & 63;
  const int w    = t >> 6;
  const int wm   = w & 1;        // wave row (0..1)
  const int wn   = w >> 1;       // wave col (0..1)
  const int tileM = blockIdx.y * BM;
  const int tileN = blockIdx.x * BN;

  f32x4 acc[4][4] = {};

  for (int k0 = 0; k0 < K; k0 += BKT) {
    // ---- stage A and B tiles: 128 rows x 64 bf16 = 8 chunks(16B)/row.
    // LDS slot (row, cc) holds global chunk (row, cc ^ (row&7))  [XOR swizzle]
#pragma unroll
    for (int i = 0; i < 4; ++i) {
      const int c   = t + 256 * i;       // chunk id 0..1023
      const int row = c >> 3;
      const int cc  = c & 7;
      const int gcc = cc ^ (row & 7);
      const int ldsbase = ((t & ~63) + 256 * i) * 8;  // wave-uniform, elements
      const bf16_t* ga = A + (long long)(tileM + row) * K + k0 + gcc * 8;
      async_copy16(ga, &As[ldsbase]);
      const bf16_t* gb = B + (long long)(tileN + row) * K + k0 + gcc * 8;
      async_copy16(gb, &Bs[ldsbase]);
    }
    __syncthreads();

#pragma unroll
    for (int s = 0; s < 2; ++s) {
      bf16x8 af[4], bfr[4];
      const int kc = s * 4 + (lane >> 4);
#pragma unroll
      for (int ti = 0; ti < 4; ++ti) {
        const int row = wm * 64 + ti * 16 + (lane & 15);
        const int off = row * BKT + ((kc ^ (row & 7)) * 8);
        af[ti] = *(const bf16x8*)&As[off];
      }
#pragma unroll
      for (int tj = 0; tj < 4; ++tj) {
        const int row = wn * 64 + tj * 16 + (lane & 15);
        const int off = row * BKT + ((kc ^ (row & 7)) * 8);
        bfr[tj] = *(const bf16x8*)&Bs[off];
      }
#pragma unroll
      for (int ti = 0; ti < 4; ++ti)
#pragma unroll
        for (int tj = 0; tj < 4; ++tj)
          acc[ti][tj] = __builtin_amdgcn_mfma_f32_16x16x32_bf16(
              af[ti], bfr[tj], acc[ti][tj], 0, 0, 0);
    }
    __syncthreads();
  }

  // ---- epilogue: C mapping col = lane&15, row = (lane>>4)*4 + r
#pragma unroll
  for (int tj = 0; tj < 4; ++tj) {
    const int col = tileN + wn * 64 + tj * 16 + (lane & 15);
    const float bv = HasBias ? bias[col] : 0.f;
#pragma unroll
    for (int ti = 0; ti < 4; ++ti) {
      const int row0 = tileM + wm * 64 + ti * 16 + (lane >> 4) * 4;
#pragma unroll
      for (int r = 0; r < 4; ++r) {
        const float v = acc[ti][tj][r] * scale + bv;
        store_out(&C[(long long)(row0 + r) * N + col], v);
      }
    }
  }
}

// ---------------------------------------------------------------------------
// fp32 -> bf16 cast, vectorized x4
// ---------------------------------------------------------------------------
__global__ __launch_bounds__(256) void cast_f32_bf16(
    const float4* __restrict__ in, bf16x4* __restrict__ out, int n4) {
  const int i = blockIdx.x * 256 + threadIdx.x;
  if (i >= n4) return;
  const float4 v = in[i];
  bf16x4 o;
  o[0] = (bf16_t)v.x; o[1] = (bf16_t)v.y; o[2] = (bf16_t)v.z; o[3] = (bf16_t)v.w;
  out[i] = o;
}

// ---------------------------------------------------------------------------
// bf16 transpose [R,C] -> [C,R], batched via blockIdx.z (stride R*C)
// ---------------------------------------------------------------------------
__global__ __launch_bounds__(256) void transpose_bf16(
    const bf16_t* __restrict__ in, bf16_t* __restrict__ out, int R, int C) {
  const long long base = (long long)blockIdx.z * R * C;
  in += base; out += base;
  __shared__ bf16_t tile[32][33];
  const int tx = threadIdx.x, ty = threadIdx.y;
  const int x = blockIdx.x * 32 + tx;
  const int y0 = blockIdx.y * 32;
#pragma unroll
  for (int j = 0; j < 32; j += 8)
    tile[ty + j][tx] = in[(long long)(y0 + ty + j) * C + x];
  __syncthreads();
  const int x2 = y0 + tx;               // row of in  -> col of out
  const int y2 = blockIdx.x * 32;       // col of in  -> row of out
#pragma unroll
  for (int j = 0; j < 32; j += 8)
    out[(long long)(y2 + ty + j) * R + x2] = tile[tx][ty + j];
}

// ---------------------------------------------------------------------------
// row softmax: S[row][cols] bf16 -> P[row][cols] bf16. cols = 2048, 256 thr.
// ---------------------------------------------------------------------------
__global__ __launch_bounds__(256) void softmax_rows(
    const bf16_t* __restrict__ S, bf16_t* __restrict__ P, int cols) {
  const long long row = blockIdx.x;
  const bf16x8* inp = (const bf16x8*)(S + row * cols);
  bf16x8* outp      = (bf16x8*)(P + row * cols);
  const int t = threadIdx.x;
  const int w = t >> 6, lane = t & 63;

  const bf16x8 v = inp[t];
  float f[8];
#pragma unroll
  for (int j = 0; j < 8; ++j) f[j] = (float)v[j];

  float m = f[0];
#pragma unroll
  for (int j = 1; j < 8; ++j) m = fmaxf(m, f[j]);
#pragma unroll
  for (int off = 32; off > 0; off >>= 1) m = fmaxf(m, __shfl_xor(m, off));

  __shared__ float red[8];
  if (lane == 0) red[w] = m;
  __syncthreads();
  m = fmaxf(fmaxf(red[0], red[1]), fmaxf(red[2], red[3]));

  float e[8], sum = 0.f;
#pragma unroll
  for (int j = 0; j < 8; ++j) { e[j] = __expf(f[j] - m); sum += e[j]; }
#pragma unroll
  for (int off = 32; off > 0; off >>= 1) sum += __shfl_xor(sum, off);
  if (lane == 0) red[4 + w] = sum;
  __syncthreads();
  sum = red[4] + red[5] + red[6] + red[7];

  const float inv = 1.f / sum;
  bf16x8 o;
#pragma unroll
  for (int j = 0; j < 8; ++j) o[j] = (bf16_t)(e[j] * inv);
  outp[t] = o;
}

// ---------------------------------------------------------------------------
extern "C" void kernel_launch(void* const* d_in, const int* in_sizes, int n_in,
                              void* d_out, int out_size, void* d_ws, size_t ws_size,
                              hipStream_t stream) {
  const int E = 1024, S = 2048, B = 4;
  const int BS = B * S;  // 8192

  const float* x  = (const float*)d_in[0];
  const float* Wq = (const float*)d_in[1];
  const float* bq = (const float*)d_in[2];
  const float* Wk = (const float*)d_in[3];
  const float* bk = (const float*)d_in[4];
  const float* Wv = (const float*)d_in[5];
  const float* bv = (const float*)d_in[6];
  const float* Wo = (const float*)d_in[7];
  const float* bo = (const float*)d_in[8];
  float* out = (float*)d_out;

  char* w = (char*)d_ws;
  const size_t MB = 1ull << 20;
  bf16_t* Wqb = (bf16_t*)(w + 0 * MB);   // 2 MB each
  bf16_t* Wkb = (bf16_t*)(w + 2 * MB);
  bf16_t* Wvb = (bf16_t*)(w + 4 * MB);
  bf16_t* Wob = (bf16_t*)(w + 6 * MB);
  bf16_t* xb  = (bf16_t*)(w + 8 * MB);   // 16 MB
  bf16_t* Qb  = (bf16_t*)(w + 24 * MB);  // 16 MB
  bf16_t* Kb  = (bf16_t*)(w + 40 * MB);  // 16 MB
  bf16_t* Vb  = (bf16_t*)(w + 56 * MB);  // 16 MB
  bf16_t* VTb = (bf16_t*)(w + 72 * MB);  // 16 MB
  bf16_t* Sb  = (bf16_t*)(w + 88 * MB);  // 32 MB (bf16 scores) -> ends 120 MB
  bf16_t* Pb  = (bf16_t*)(w + 8 * MB);   // reuse xb+Qb region (32 MB); both dead
  bf16_t* Ob  = (bf16_t*)(w + 56 * MB);  // reuse Vb region (16 MB); V dead

  // ---- casts to bf16
  {
    const int n4w = E * E / 4;                   // 262144
    const int gw = (n4w + 255) / 256;
    cast_f32_bf16<<<gw, 256, 0, stream>>>((const float4*)Wq, (bf16x4*)Wqb, n4w);
    cast_f32_bf16<<<gw, 256, 0, stream>>>((const float4*)Wk, (bf16x4*)Wkb, n4w);
    cast_f32_bf16<<<gw, 256, 0, stream>>>((const float4*)Wv, (bf16x4*)Wvb, n4w);
    cast_f32_bf16<<<gw, 256, 0, stream>>>((const float4*)Wo, (bf16x4*)Wob, n4w);
    const int n4x = BS * E / 4;                  // 2097152
    cast_f32_bf16<<<(n4x + 255) / 256, 256, 0, stream>>>((const float4*)x, (bf16x4*)xb, n4x);
  }

  // ---- Q/K/V projections: [8192,1024] = xb[8192,1024] . W[1024,1024]^T + b
  {
    dim3 g(E / BN, BS / BM, 1);  // (8, 64)
    gemm_bt<bf16_t, true><<<g, 256, 0, stream>>>(xb, Wqb, Qb, bq, BS, E, E, 1.f, 0, 0, 0);
    gemm_bt<bf16_t, true><<<g, 256, 0, stream>>>(xb, Wkb, Kb, bk, BS, E, E, 1.f, 0, 0, 0);
    gemm_bt<bf16_t, true><<<g, 256, 0, stream>>>(xb, Wvb, Vb, bv, BS, E, E, 1.f, 0, 0, 0);
  }

  // ---- V^T per batch: [2048,1024] -> [1024,2048]
  {
    dim3 g(E / 32, S / 32, B);
    transpose_bf16<<<g, dim3(32, 8), 0, stream>>>(Vb, VTb, S, E);
  }

  // ---- scores = Q . K^T * E^-0.5 : per-batch [2048,2048]
  {
    dim3 g(S / BN, S / BM, B);  // (16,16,4)
    gemm_bt<bf16_t, false><<<g, 256, 0, stream>>>(
        Qb, Kb, Sb, nullptr, S, S, E, 0.03125f,
        (long long)S * E, (long long)S * E, (long long)S * S);
  }

  // ---- softmax rows (8192 rows of 2048)
  softmax_rows<<<BS, 256, 0, stream>>>(Sb, Pb, S);

  // ---- O = P . V  (= P . (V^T)^T): per-batch [2048,1024]
  {
    dim3 g(E / BN, S / BM, B);  // (8,16,4)
    gemm_bt<bf16_t, false><<<g, 256, 0, stream>>>(
        Pb, VTb, Ob, nullptr, S, E, S, 1.f,
        (long long)S * S, (long long)E * S, (long long)S * E);
  }

  // ---- y = O . Wo^T + bo -> fp32 output
  {
    dim3 g(E / BN, BS / BM, 1);  // (8,64)
    gemm_bt<float, true><<<g, 256, 0, stream>>>(Ob, Wob, out, bo, BS, E, E, 1.f, 0, 0, 0);
  }
}

// Round 2
// 296.222 us; speedup vs baseline: 1.0892x; 1.0892x over previous
//
#include <hip/hip_runtime.h>
#include <hip/hip_bf16.h>

// ---------------------------------------------------------------------------
// SelfAttentionHybrid: single-head attention, B=4 S=2048 E=1024, fp32 in/out.
// R2: 32x32x16 MFMA (half the MFMA instr count of 16x16x32), fused QKV GEMM
// (N=3072, strided C), fused weight-cast dispatch. 8 dispatches total.
// ---------------------------------------------------------------------------

typedef __bf16 bf16_t;
typedef __bf16 bf16x8 __attribute__((ext_vector_type(8)));
typedef __bf16 bf16x4 __attribute__((ext_vector_type(4)));
typedef float  f32x16 __attribute__((ext_vector_type(16)));

__device__ __forceinline__ void async_copy16(const void* g, void* l) {
  __builtin_amdgcn_global_load_lds(
      (const __attribute__((address_space(1))) void*)g,
      (__attribute__((address_space(3))) void*)l, 16, 0, 0);
}

__device__ __forceinline__ void store_out(float* p, float v)  { *p = v; }
__device__ __forceinline__ void store_out(bf16_t* p, float v) { *p = (bf16_t)v; }

#define BM 128
#define BN 128
#define BKT 64

// ---------------------------------------------------------------------------
// C[M,N] = A[M,K](lda) x B[N,K](ldb)^T * scale + bias, bf16 in, fp32 acc.
// 256 thr = 4 waves (2x2); wave tile 64x64 = 2x2 of 32x32x16 MFMA.
// NBIAS: 0 = none, 1 = bias b0[N], 3 = concat b0|b1|b2 (1024 each).
// ---------------------------------------------------------------------------
template <typename OutT, int NBIAS>
__global__ __launch_bounds__(256) void gemm_bt(
    const bf16_t* __restrict__ A, const bf16_t* __restrict__ B,
    OutT* __restrict__ C,
    const float* __restrict__ b0, const float* __restrict__ b1,
    const float* __restrict__ b2,
    int M, int N, int K, int lda, int ldb, int ldc, float scale,
    long long strideA, long long strideB, long long strideC) {
  const int z = blockIdx.z;
  A += (long long)z * strideA;
  B += (long long)z * strideB;
  C += (long long)z * strideC;

  __shared__ __align__(16) bf16_t As[BM * BKT];  // 16 KB
  __shared__ __align__(16) bf16_t Bs[BN * BKT];  // 16 KB

  const int t    = threadIdx.x;
  const int lane = t & 63;
  const int w    = t >> 6;
  const int wm   = w & 1;
  const int wn   = w >> 1;
  const int tileM = blockIdx.y * BM;
  const int tileN = blockIdx.x * BN;

  f32x16 acc[2][2] = {};

  for (int k0 = 0; k0 < K; k0 += BKT) {
    // stage 128 rows x 64 bf16 per matrix; 16B chunks, XOR swizzle on chunk col
#pragma unroll
    for (int i = 0; i < 4; ++i) {
      const int c   = t + 256 * i;
      const int row = c >> 3;
      const int cc  = c & 7;
      const int gcc = cc ^ (row & 7);
      const int ldsbase = ((t & ~63) + 256 * i) * 8;  // wave-uniform base (elems)
      async_copy16(A + (long long)(tileM + row) * lda + k0 + gcc * 8, &As[ldsbase]);
      async_copy16(B + (long long)(tileN + row) * ldb + k0 + gcc * 8, &Bs[ldsbase]);
    }
    __syncthreads();

#pragma unroll
    for (int s = 0; s < 4; ++s) {        // k-step of 16
      const int kc = s * 2 + (lane >> 5);
      bf16x8 af[2], bfr[2];
#pragma unroll
      for (int ti = 0; ti < 2; ++ti) {
        const int row = wm * 64 + ti * 32 + (lane & 31);
        af[ti] = *(const bf16x8*)&As[row * BKT + ((kc ^ (row & 7)) * 8)];
      }
#pragma unroll
      for (int tj = 0; tj < 2; ++tj) {
        const int row = wn * 64 + tj * 32 + (lane & 31);
        bfr[tj] = *(const bf16x8*)&Bs[row * BKT + ((kc ^ (row & 7)) * 8)];
      }
#pragma unroll
      for (int ti = 0; ti < 2; ++ti)
#pragma unroll
        for (int tj = 0; tj < 2; ++tj)
          acc[ti][tj] = __builtin_amdgcn_mfma_f32_32x32x16_bf16(
              af[ti], bfr[tj], acc[ti][tj], 0, 0, 0);
    }
    __syncthreads();
  }

  // epilogue: 32x32 C map: col = lane&31, row = (r&3) + 8*(r>>2) + 4*(lane>>5)
#pragma unroll
  for (int tj = 0; tj < 2; ++tj) {
    const int col = tileN + wn * 64 + tj * 32 + (lane & 31);
    float bv = 0.f;
    if (NBIAS == 1) bv = b0[col];
    if (NBIAS == 3) {
      const float* bp = col < 1024 ? b0 : (col < 2048 ? b1 : b2);
      bv = bp[col & 1023];
    }
#pragma unroll
    for (int ti = 0; ti < 2; ++ti) {
      const int rowb = tileM + wm * 64 + ti * 32 + 4 * (lane >> 5);
#pragma unroll
      for (int r = 0; r < 16; ++r) {
        const int row = rowb + (r & 3) + 8 * (r >> 2);
        store_out(&C[(long long)row * ldc + col], acc[ti][tj][r] * scale + bv);
      }
    }
  }
}

// ---------------------------------------------------------------------------
// fused weight cast: 4 fp32 [E,E] matrices -> one contiguous bf16 buffer
// (Wq|Wk|Wv|Wo). blockIdx.z selects source.
// ---------------------------------------------------------------------------
__global__ __launch_bounds__(256) void cast_weights(
    const float4* __restrict__ w0, const float4* __restrict__ w1,
    const float4* __restrict__ w2, const float4* __restrict__ w3,
    bf16x4* __restrict__ dst, int n4) {
  const int z = blockIdx.z;
  const float4* src = z == 0 ? w0 : (z == 1 ? w1 : (z == 2 ? w2 : w3));
  const int i = blockIdx.x * 256 + threadIdx.x;
  if (i >= n4) return;
  const float4 v = src[i];
  bf16x4 o;
  o[0] = (bf16_t)v.x; o[1] = (bf16_t)v.y; o[2] = (bf16_t)v.z; o[3] = (bf16_t)v.w;
  dst[(long long)z * n4 + i] = o;
}

__global__ __launch_bounds__(256) void cast_f32_bf16(
    const float4* __restrict__ in, bf16x4* __restrict__ out, int n4) {
  const int i = blockIdx.x * 256 + threadIdx.x;
  if (i >= n4) return;
  const float4 v = in[i];
  bf16x4 o;
  o[0] = (bf16_t)v.x; o[1] = (bf16_t)v.y; o[2] = (bf16_t)v.z; o[3] = (bf16_t)v.w;
  out[i] = o;
}

// ---------------------------------------------------------------------------
// bf16 transpose [R,C](ldin) -> [C,R], batched via blockIdx.z
// ---------------------------------------------------------------------------
__global__ __launch_bounds__(256) void transpose_bf16(
    const bf16_t* __restrict__ in, bf16_t* __restrict__ out, int R, int C,
    int ldin, long long sIn, long long sOut) {
  in  += (long long)blockIdx.z * sIn;
  out += (long long)blockIdx.z * sOut;
  __shared__ bf16_t tile[32][33];
  const int tx = threadIdx.x, ty = threadIdx.y;
  const int x = blockIdx.x * 32 + tx;
  const int y0 = blockIdx.y * 32;
#pragma unroll
  for (int j = 0; j < 32; j += 8)
    tile[ty + j][tx] = in[(long long)(y0 + ty + j) * ldin + x];
  __syncthreads();
  const int x2 = y0 + tx;
  const int y2 = blockIdx.x * 32;
#pragma unroll
  for (int j = 0; j < 32; j += 8)
    out[(long long)(y2 + ty + j) * R + x2] = tile[tx][ty + j];
}

// ---------------------------------------------------------------------------
// row softmax: 2048-wide rows, 256 threads x 8 elems
// ---------------------------------------------------------------------------
__global__ __launch_bounds__(256) void softmax_rows(
    const bf16_t* __restrict__ S, bf16_t* __restrict__ P, int cols) {
  const long long row = blockIdx.x;
  const bf16x8* inp = (const bf16x8*)(S + row * cols);
  bf16x8* outp      = (bf16x8*)(P + row * cols);
  const int t = threadIdx.x;
  const int w = t >> 6, lane = t & 63;

  const bf16x8 v = inp[t];
  float f[8];
#pragma unroll
  for (int j = 0; j < 8; ++j) f[j] = (float)v[j];

  float m = f[0];
#pragma unroll
  for (int j = 1; j < 8; ++j) m = fmaxf(m, f[j]);
#pragma unroll
  for (int off = 32; off > 0; off >>= 1) m = fmaxf(m, __shfl_xor(m, off));

  __shared__ float red[8];
  if (lane == 0) red[w] = m;
  __syncthreads();
  m = fmaxf(fmaxf(red[0], red[1]), fmaxf(red[2], red[3]));

  float e[8], sum = 0.f;
#pragma unroll
  for (int j = 0; j < 8; ++j) { e[j] = __expf(f[j] - m); sum += e[j]; }
#pragma unroll
  for (int off = 32; off > 0; off >>= 1) sum += __shfl_xor(sum, off);
  if (lane == 0) red[4 + w] = sum;
  __syncthreads();
  sum = red[4] + red[5] + red[6] + red[7];

  const float inv = 1.f / sum;
  bf16x8 o;
#pragma unroll
  for (int j = 0; j < 8; ++j) o[j] = (bf16_t)(e[j] * inv);
  outp[t] = o;
}

// ---------------------------------------------------------------------------
extern "C" void kernel_launch(void* const* d_in, const int* in_sizes, int n_in,
                              void* d_out, int out_size, void* d_ws, size_t ws_size,
                              hipStream_t stream) {
  const int E = 1024, S = 2048, B = 4;
  const int BS = B * S;  // 8192

  const float* x  = (const float*)d_in[0];
  const float* Wq = (const float*)d_in[1];
  const float* bq = (const float*)d_in[2];
  const float* Wk = (const float*)d_in[3];
  const float* bk = (const float*)d_in[4];
  const float* Wv = (const float*)d_in[5];
  const float* bv = (const float*)d_in[6];
  const float* Wo = (const float*)d_in[7];
  const float* bo = (const float*)d_in[8];
  float* out = (float*)d_out;

  char* w = (char*)d_ws;
  const size_t MB = 1ull << 20;
  bf16_t* Wqkvb = (bf16_t*)(w + 0 * MB);          // 6 MB  [3072,1024]
  bf16_t* Wob   = Wqkvb + 3 * E * E;              // 2 MB  (contiguous after)
  bf16_t* xb    = (bf16_t*)(w + 8 * MB);          // 16 MB [8192,1024]
  bf16_t* QKVb  = (bf16_t*)(w + 24 * MB);         // 48 MB [8192,3072]
  bf16_t* VTb   = (bf16_t*)(w + 72 * MB);         // 16 MB [B][1024,2048]
  bf16_t* Sb    = (bf16_t*)(w + 88 * MB);         // 32 MB scores
  bf16_t* Pb    = (bf16_t*)(w + 8 * MB);          // 32 MB (xb + QKV[0:16MB] dead)
  bf16_t* Ob    = (bf16_t*)(w + 40 * MB);         // 16 MB (QKV[16:32MB] dead)

  // ---- casts (2 dispatches)
  const int n4w = E * E / 4;
  cast_weights<<<dim3((n4w + 255) / 256, 1, 4), 256, 0, stream>>>(
      (const float4*)Wq, (const float4*)Wk, (const float4*)Wv, (const float4*)Wo,
      (bf16x4*)Wqkvb, n4w);
  const int n4x = BS * E / 4;
  cast_f32_bf16<<<(n4x + 255) / 256, 256, 0, stream>>>(
      (const float4*)x, (bf16x4*)xb, n4x);

  // ---- fused QKV projection: [8192,3072] = xb . Wqkv^T + (bq|bk|bv)
  gemm_bt<bf16_t, 3><<<dim3(3 * E / BN, BS / BM, 1), 256, 0, stream>>>(
      xb, Wqkvb, QKVb, bq, bk, bv,
      BS, 3 * E, E, E, E, 3 * E, 1.f, 0, 0, 0);

  // ---- V^T per batch: [2048,1024](ld 3072) -> [1024,2048]
  transpose_bf16<<<dim3(E / 32, S / 32, B), dim3(32, 8), 0, stream>>>(
      QKVb + 2 * E, VTb, S, E, 3 * E, (long long)S * 3 * E, (long long)E * S);

  // ---- scores = Q . K^T * E^-0.5 per batch
  gemm_bt<bf16_t, 0><<<dim3(S / BN, S / BM, B), 256, 0, stream>>>(
      QKVb, QKVb + E, Sb, nullptr, nullptr, nullptr,
      S, S, E, 3 * E, 3 * E, S, 0.03125f,
      (long long)S * 3 * E, (long long)S * 3 * E, (long long)S * S);

  // ---- softmax
  softmax_rows<<<BS, 256, 0, stream>>>(Sb, Pb, S);

  // ---- O = P . (V^T)^T per batch
  gemm_bt<bf16_t, 0><<<dim3(E / BN, S / BM, B), 256, 0, stream>>>(
      Pb, VTb, Ob, nullptr, nullptr, nullptr,
      S, E, S, S, S, E, 1.f,
      (long long)S * S, (long long)E * S, (long long)S * E);

  // ---- y = O . Wo^T + bo
  gemm_bt<float, 1><<<dim3(E / BN, BS / BM, 1), 256, 0, stream>>>(
      Ob, Wob, out, bo, nullptr, nullptr,
      BS, E, E, E, E, E, 1.f, 0, 0, 0);
}